// Round 10
// baseline (275.679 us; speedup 1.0000x reference)
//
#include <hip/hip_runtime.h>
#include <cstdint>

typedef unsigned short u16;
typedef __attribute__((ext_vector_type(8))) short short8;
typedef __attribute__((ext_vector_type(4))) float floatx4;

#define BT    8192
#define TSEQ  2048
#define NBAT  4
#define CMOD  512
#define NH    4
#define HD    128
#define DFF   2048
#define CQKV  1536

__device__ __forceinline__ u16 f2bf(float f) {
  union { float f; uint32_t u; } v; v.f = f;
  uint32_t r = v.u + 0x7FFFu + ((v.u >> 16) & 1u);
  return (u16)(r >> 16);
}
__device__ __forceinline__ float bf2f(u16 u) {
  union { uint32_t u; float f; } v; v.u = ((uint32_t)u) << 16; return v.f;
}
__device__ __forceinline__ float exp2a(float x) {
  float r; asm("v_exp_f32 %0, %1" : "=v"(r) : "v"(x)); return r;
}
__device__ __forceinline__ float rcpa(float x) {
  float r; asm("v_rcp_f32 %0, %1" : "=v"(r) : "v"(x)); return r;
}

typedef __attribute__((address_space(1))) const unsigned int ga_u32;
typedef __attribute__((address_space(3))) unsigned int ls_u32;
__device__ __forceinline__ void glds16(const u16* g, u16* l) {
  __builtin_amdgcn_global_load_lds((ga_u32*)g, (ls_u32*)l, 16, 0, 0);
}

// ---------------- fused prep: 4 weight transposes + LN1 (proven) ----------------
__device__ __forceinline__ void tcast_body(const float* __restrict__ W, u16* __restrict__ Wt,
                                           int K, int N, int bx, int by, int tid,
                                           float (*tile)[33]) {
  int n0 = bx * 32, k0 = by * 32;
  int tx = tid & 31, ty = tid >> 5;
  #pragma unroll
  for (int r = 0; r < 32; r += 8)
    tile[r + ty][tx] = W[(size_t)(k0 + r + ty) * N + n0 + tx];
  __syncthreads();
  #pragma unroll
  for (int r = 0; r < 32; r += 8)
    Wt[(size_t)(n0 + r + ty) * K + k0 + tx] = f2bf(tile[tx][r + ty]);
}

__global__ __launch_bounds__(256) void prep_kernel(
    const float* __restrict__ x, const float* __restrict__ g, const float* __restrict__ b,
    const float* __restrict__ wqkv, const float* __restrict__ wproj,
    const float* __restrict__ wff1, const float* __restrict__ wff2,
    u16* __restrict__ ln_out, u16* __restrict__ wqkvT, u16* __restrict__ wprojT,
    u16* __restrict__ wff1T, u16* __restrict__ wff2T) {
  __shared__ float tile[32][33];
  int bid = blockIdx.x, tid = threadIdx.x;
  if (bid < 768) {
    tcast_body(wqkv, wqkvT, CMOD, CQKV, bid % 48, bid / 48, tid, tile);
  } else if (bid < 1024) {
    int id = bid - 768; tcast_body(wproj, wprojT, CMOD, CMOD, id % 16, id / 16, tid, tile);
  } else if (bid < 2048) {
    int id = bid - 1024; tcast_body(wff1, wff1T, CMOD, DFF, id % 64, id / 64, tid, tile);
  } else if (bid < 3072) {
    int id = bid - 2048; tcast_body(wff2, wff2T, DFF, CMOD, id % 16, id / 16, tid, tile);
  } else {
    int row = (bid - 3072) * 4 + (tid >> 6);
    int lane = tid & 63;
    const float4* xr = (const float4*)(x + (size_t)row * CMOD);
    float4 a = xr[lane], c = xr[lane + 64];
    float s = a.x + a.y + a.z + a.w + c.x + c.y + c.z + c.w;
    float q = a.x*a.x + a.y*a.y + a.z*a.z + a.w*a.w
            + c.x*c.x + c.y*c.y + c.z*c.z + c.w*c.w;
    #pragma unroll
    for (int o = 32; o; o >>= 1) { s += __shfl_xor(s, o); q += __shfl_xor(q, o); }
    float mu = s * (1.0f / CMOD);
    float rstd = rsqrtf(q * (1.0f / CMOD) - mu * mu + 1e-5f);
    const float4* gr = (const float4*)g;
    const float4* br = (const float4*)b;
    float4 g0 = gr[lane], g1 = gr[lane + 64], b0 = br[lane], b1 = br[lane + 64];
    u16* orow = ln_out + (size_t)row * CMOD;
    int i0 = lane * 4, i1 = (lane + 64) * 4;
    orow[i0 + 0] = f2bf((a.x - mu) * rstd * g0.x + b0.x);
    orow[i0 + 1] = f2bf((a.y - mu) * rstd * g0.y + b0.y);
    orow[i0 + 2] = f2bf((a.z - mu) * rstd * g0.z + b0.z);
    orow[i0 + 3] = f2bf((a.w - mu) * rstd * g0.w + b0.w);
    orow[i1 + 0] = f2bf((c.x - mu) * rstd * g1.x + b1.x);
    orow[i1 + 1] = f2bf((c.y - mu) * rstd * g1.y + b1.y);
    orow[i1 + 2] = f2bf((c.z - mu) * rstd * g1.z + b1.z);
    orow[i1 + 3] = f2bf((c.w - mu) * rstd * g1.w + b1.w);
  }
}

// ---------------- layernorm (standalone, for LN2; proven) ----------------
__global__ __launch_bounds__(256) void ln_kernel(const float* __restrict__ x,
                                                 const float* __restrict__ g,
                                                 const float* __restrict__ b,
                                                 u16* __restrict__ out) {
  int row = blockIdx.x * 4 + (threadIdx.x >> 6);
  int lane = threadIdx.x & 63;
  const float4* xr = (const float4*)(x + (size_t)row * CMOD);
  float4 a = xr[lane], c = xr[lane + 64];
  float s = a.x + a.y + a.z + a.w + c.x + c.y + c.z + c.w;
  float q = a.x*a.x + a.y*a.y + a.z*a.z + a.w*a.w
          + c.x*c.x + c.y*c.y + c.z*c.z + c.w*c.w;
  #pragma unroll
  for (int o = 32; o; o >>= 1) { s += __shfl_xor(s, o); q += __shfl_xor(q, o); }
  float mu = s * (1.0f / CMOD);
  float rstd = rsqrtf(q * (1.0f / CMOD) - mu * mu + 1e-5f);
  const float4* gr = (const float4*)g;
  const float4* br = (const float4*)b;
  float4 g0 = gr[lane], g1 = gr[lane + 64], b0 = br[lane], b1 = br[lane + 64];
  u16* orow = out + (size_t)row * CMOD;
  int i0 = lane * 4, i1 = (lane + 64) * 4;
  orow[i0 + 0] = f2bf((a.x - mu) * rstd * g0.x + b0.x);
  orow[i0 + 1] = f2bf((a.y - mu) * rstd * g0.y + b0.y);
  orow[i0 + 2] = f2bf((a.z - mu) * rstd * g0.z + b0.z);
  orow[i0 + 3] = f2bf((a.w - mu) * rstd * g0.w + b0.w);
  orow[i1 + 0] = f2bf((c.x - mu) * rstd * g1.x + b1.x);
  orow[i1 + 1] = f2bf((c.y - mu) * rstd * g1.y + b1.y);
  orow[i1 + 2] = f2bf((c.z - mu) * rstd * g1.z + b1.z);
  orow[i1 + 3] = f2bf((c.w - mu) * rstd * g1.w + b1.w);
}

// ---------------- MFMA GEMM (R7-proven) ----------------
template <int EPI, int TN>
__global__ __launch_bounds__(256, 4) void gemm_kernel(
    const u16* __restrict__ A, const u16* __restrict__ Bt, int K,
    const float* __restrict__ resid, float* __restrict__ outf,
    u16* __restrict__ ob0, u16* __restrict__ ob1, u16* __restrict__ ob2) {
  constexpr int WNF = TN / 32;
  constexpr int NKB = TN / 64;
  __shared__ __align__(16) u16 As[2][128 * 32];
  __shared__ __align__(16) u16 Bs[2][TN * 32];
  int tid = threadIdx.x;
  int lane = tid & 63, wave = tid >> 6;
  int lane16 = lane & 15, quad = lane >> 4;
  int m0 = blockIdx.y * 128, n0 = blockIdx.x * TN;
  int wm = (wave >> 1) * 64, wn = (wave & 1) * (TN / 2);

  floatx4 acc[4][WNF];
  #pragma unroll
  for (int i = 0; i < 4; i++)
    #pragma unroll
    for (int j = 0; j < WNF; j++) acc[i][j] = (floatx4)(0.0f);

  const u16* agp[2]; u16* alp[2][2];
  const u16* bgp[NKB]; u16* blp[NKB][2];
  #pragma unroll
  for (int i = 0; i < 2; i++) {
    int s = i * 256 + tid;
    agp[i] = A + (size_t)(m0 + (s >> 2)) * K + (s & 3) * 8;
    alp[i][0] = &As[0][(i * 256 + wave * 64) * 8];
    alp[i][1] = &As[1][(i * 256 + wave * 64) * 8];
  }
  #pragma unroll
  for (int i = 0; i < NKB; i++) {
    int s = i * 256 + tid;
    bgp[i] = Bt + (size_t)(n0 + (s >> 2)) * K + (s & 3) * 8;
    blp[i][0] = &Bs[0][(i * 256 + wave * 64) * 8];
    blp[i][1] = &Bs[1][(i * 256 + wave * 64) * 8];
  }

  int nk = K >> 5;
  #pragma unroll
  for (int i = 0; i < 2; i++) glds16(agp[i], alp[i][0]);
  #pragma unroll
  for (int i = 0; i < NKB; i++) glds16(bgp[i], blp[i][0]);

  for (int kt = 0; kt < nk; kt++) {
    __syncthreads();
    int buf = kt & 1;
    if (kt + 1 < nk) {
      int k1 = (kt + 1) * 32;
      #pragma unroll
      for (int i = 0; i < 2; i++) glds16(agp[i] + k1, alp[i][buf ^ 1]);
      #pragma unroll
      for (int i = 0; i < NKB; i++) glds16(bgp[i] + k1, blp[i][buf ^ 1]);
    }
    short8 af[4];
    #pragma unroll
    for (int i = 0; i < 4; i++)
      af[i] = *(const short8*)&As[buf][(wm + i * 16 + lane16) * 32 + quad * 8];
    #pragma unroll
    for (int j = 0; j < WNF; j++) {
      short8 bfj = *(const short8*)&Bs[buf][(wn + j * 16 + lane16) * 32 + quad * 8];
      #pragma unroll
      for (int i = 0; i < 4; i++)
        acc[i][j] = __builtin_amdgcn_mfma_f32_16x16x32_bf16(af[i], bfj, acc[i][j], 0, 0, 0);
    }
  }

  #pragma unroll
  for (int i = 0; i < 4; i++) {
    #pragma unroll
    for (int j = 0; j < WNF; j++) {
      #pragma unroll
      for (int r = 0; r < 4; r++) {
        int m = m0 + wm + i * 16 + quad * 4 + r;
        int n = n0 + wn + j * 16 + lane16;
        float v = acc[i][j][r];
        if (EPI == 0) {
          int bb = m >> 11, t = m & 2047;
          int nn = n & 511, which = n >> 9;
          int h = nn >> 7, d = nn & 127;
          size_t bh = (size_t)(bb * NH + h);
          if (which == 0)      ob0[bh * TSEQ * HD + (size_t)t * HD + d] = f2bf(v * 0.12751743f);
          else if (which == 1) ob1[bh * TSEQ * HD + (size_t)t * HD + d] = f2bf(v);
          else                 ob2[bh * HD * TSEQ + (size_t)d * TSEQ + t] = f2bf(v);
        } else if (EPI == 1) {
          size_t idx = (size_t)m * CMOD + n;
          outf[idx] = v + resid[idx];
        } else if (EPI == 2) {
          float ge = 0.5f * v * (1.0f + erff(v * 0.70710678118654752f));
          ob0[(size_t)m * DFF + n] = f2bf(ge);
        } else {
          size_t idx = (size_t)m * CMOD + n;
          outf[idx] = v + resid[idx];
        }
      }
    }
  }
}

// ---------------- flash attention v8: dual-q (32 q/wave), NO direct-write, NO vgpr cap ----
// 256 threads, 4 waves; block covers 128 q-rows. Dual A-frags/P-rows/accumulators.
// Staging/dbuf verbatim R7. ALL blocks write partials (R4/R7-proven epilogue shape);
// reduce covers every qq. Plain launch bounds: no forced spills.
__global__ __launch_bounds__(256) void attn_kernel(const u16* __restrict__ qb,
                                                   const u16* __restrict__ kb,
                                                   const u16* __restrict__ vtb,
                                                   u16* __restrict__ po,
                                                   float* __restrict__ pl) {
  __shared__ __align__(16) u16 Ks[2][32 * 128];
  __shared__ __align__(16) u16 Vs[2][128 * 32];
  __shared__ __align__(16) uint32_t Ps[4 * 32 * 20];  // 4 waves x 32 rows x 20 dw
  int tid = threadIdx.x, wave = tid >> 6, lane = tid & 63;
  int lane16 = lane & 15, quad = lane >> 4;
  int bh = blockIdx.x;
  int cid = (int)blockIdx.y;  // cid 0 = heaviest (qq=15), dispatched first
  int qq, c;
  if (cid < 16)      { qq = 15 - (cid >> 2);           c = cid & 3; }
  else if (cid < 28) { int t = cid - 16; qq = 11 - t / 3; c = t % 3; }
  else if (cid < 36) { int t = cid - 28; qq = 7 - (t >> 1); c = t & 1; }
  else               { qq = 39 - cid;                  c = 0; }

  int q0w = qq * 128 + wave * 32;  // this wave's first q row (owns 32 rows)
  const u16* Q  = qb  + (size_t)bh * TSEQ * HD;
  const u16* Kg = kb  + (size_t)bh * TSEQ * HD;
  const u16* Vg = vtb + (size_t)bh * HD * TSEQ;

  short8 aqA[4], aqB[4];
  #pragma unroll
  for (int cc = 0; cc < 4; cc++) {
    aqA[cc] = *(const short8*)&Q[(size_t)(q0w + lane16) * HD + cc * 32 + quad * 8];
    aqB[cc] = *(const short8*)&Q[(size_t)(q0w + 16 + lane16) * HD + cc * 32 + quad * 8];
  }

  // staging pointers: VERBATIM R7 (2 issues x 256 threads for K and V, source-side swizzle)
  const u16* kgp[2]; const u16* vgp[2];
  u16* klp[2][2]; u16* vlp[2][2];
  #pragma unroll
  for (int i = 0; i < 2; i++) {
    int s = wave * 128 + i * 64 + lane;
    int r = s >> 4, cp = s & 15, cc = cp ^ (r & 7);
    kgp[i] = Kg + (size_t)r * HD + cc * 8;
    int d = s >> 2, cv = (s & 3) ^ ((d >> 1) & 3);
    vgp[i] = Vg + (size_t)d * TSEQ + cv * 8;
    #pragma unroll
    for (int bfr = 0; bfr < 2; bfr++) {
      klp[i][bfr] = &Ks[bfr][(wave * 128 + i * 64) * 8];
      vlp[i][bfr] = &Vs[bfr][(wave * 128 + i * 64) * 8];
    }
  }

  int ktw   = 4 * qq + wave + 1;      // causal tile count for this wave's 32 rows
  int ktblk = 4 * qq + 4;             // block tile count
  int kt0   = c * 16;
  int kend  = min(kt0 + 16, ktblk);

  floatx4 oA[8], oB[8];
  #pragma unroll
  for (int j = 0; j < 8; j++) { oA[j] = (floatx4)(0.0f); oB[j] = (floatx4)(0.0f); }
  floatx4 olA = (floatx4)(0.0f), olB = (floatx4)(0.0f);

  short8 ones;
  #pragma unroll
  for (int e = 0; e < 8; e++) ones[e] = (short)0x3F80;

  uint32_t* Pw = &Ps[wave * 640];
  int swl = lane16 & 7;
  int cvr = quad ^ ((lane16 >> 1) & 3);

  {
    int ko = kt0 * 32;
    #pragma unroll
    for (int i = 0; i < 2; i++) {
      glds16(kgp[i] + (size_t)ko * HD, klp[i][kt0 & 1]);
      glds16(vgp[i] + ko, vlp[i][kt0 & 1]);
    }
  }

  for (int kt = kt0; kt < kend; kt++) {
    __syncthreads();
    int buf = kt & 1;
    if (kt + 1 < kend) {
      int ko = (kt + 1) * 32;
      #pragma unroll
      for (int i = 0; i < 2; i++) {
        glds16(kgp[i] + (size_t)ko * HD, klp[i][buf ^ 1]);
        glds16(vgp[i] + ko, vlp[i][buf ^ 1]);
      }
    }
    if (kt >= ktw) continue;  // wave-uniform; barrier count aligned

    floatx4 sA0 = (floatx4)(0.0f), sA1 = (floatx4)(0.0f);
    floatx4 sB0 = (floatx4)(0.0f), sB1 = (floatx4)(0.0f);
    #pragma unroll
    for (int cc = 0; cc < 4; cc++) {
      short8 kf0 = *(const short8*)&Ks[buf][(lane16 * 16 + ((cc * 4 + quad) ^ swl)) * 8];
      short8 kf1 = *(const short8*)&Ks[buf][((16 + lane16) * 16 + ((cc * 4 + quad) ^ swl)) * 8];
      sA0 = __builtin_amdgcn_mfma_f32_16x16x32_bf16(aqA[cc], kf0, sA0, 0, 0, 0);
      sA1 = __builtin_amdgcn_mfma_f32_16x16x32_bf16(aqA[cc], kf1, sA1, 0, 0, 0);
      sB0 = __builtin_amdgcn_mfma_f32_16x16x32_bf16(aqB[cc], kf0, sB0, 0, 0, 0);
      sB1 = __builtin_amdgcn_mfma_f32_16x16x32_bf16(aqB[cc], kf1, sB1, 0, 0, 0);
    }
    short8 vf[8];
    #pragma unroll
    for (int j = 0; j < 8; j++)
      vf[j] = *(const short8*)&Vs[buf][((j * 16 + lane16) * 4 + cvr) * 8];

    int kg0 = kt * 32 + lane16;
    #pragma unroll
    for (int r = 0; r < 4; r++) {
      int qrA = q0w + quad * 4 + r, qrB = qrA + 16;
      float pA0 = exp2a(sA0[r]);
      float pA1 = exp2a(sA1[r]);
      float pB0 = exp2a(sB0[r]);
      float pB1 = exp2a(sB1[r]);
      if (kg0 > qrA) pA0 = 0.0f;
      if (kg0 + 16 > qrA) pA1 = 0.0f;
      if (kg0 > qrB) pB0 = 0.0f;
      if (kg0 + 16 > qrB) pB1 = 0.0f;
      Pw[(quad * 4 + r) * 20 + lane16] =
          __builtin_amdgcn_perm(__float_as_uint(pA1), __float_as_uint(pA0), 0x07060302u);
      Pw[(16 + quad * 4 + r) * 20 + lane16] =
          __builtin_amdgcn_perm(__float_as_uint(pB1), __float_as_uint(pB0), 0x07060302u);
    }
    asm volatile("s_waitcnt lgkmcnt(0)" ::: "memory");

    union { uint32_t u[4]; short8 s; } pfA, pfB;
    {
      uint32_t sel = (quad >> 1) ? 0x07060302u : 0x05040100u;
      const uint32_t* pra = &Pw[lane16 * 20 + (quad & 1) * 8];
      pfA.u[0] = __builtin_amdgcn_perm(pra[1], pra[0], sel);
      pfA.u[1] = __builtin_amdgcn_perm(pra[3], pra[2], sel);
      pfA.u[2] = __builtin_amdgcn_perm(pra[5], pra[4], sel);
      pfA.u[3] = __builtin_amdgcn_perm(pra[7], pra[6], sel);
      const uint32_t* prb = &Pw[(16 + lane16) * 20 + (quad & 1) * 8];
      pfB.u[0] = __builtin_amdgcn_perm(prb[1], prb[0], sel);
      pfB.u[1] = __builtin_amdgcn_perm(prb[3], prb[2], sel);
      pfB.u[2] = __builtin_amdgcn_perm(prb[5], prb[4], sel);
      pfB.u[3] = __builtin_amdgcn_perm(prb[7], prb[6], sel);
    }
    #pragma unroll
    for (int j = 0; j < 8; j++) {
      oA[j] = __builtin_amdgcn_mfma_f32_16x16x32_bf16(pfA.s, vf[j], oA[j], 0, 0, 0);
      oB[j] = __builtin_amdgcn_mfma_f32_16x16x32_bf16(pfB.s, vf[j], oB[j], 0, 0, 0);
    }
    olA = __builtin_amdgcn_mfma_f32_16x16x32_bf16(pfA.s, ones, olA, 0, 0, 0);
    olB = __builtin_amdgcn_mfma_f32_16x16x32_bf16(pfB.s, ones, olB, 0, 0, 0);
  }

  // ALWAYS write partials (R4/R7-proven epilogue shape)
  int slot = (bh * 16 + qq) * 4 + c;
  u16* pob = po + (size_t)slot * 16384;   // 128 rows x 128 cols bf16
  #pragma unroll
  for (int r = 0; r < 4; r++) {
    int qrA = wave * 32 + quad * 4 + r, qrB = qrA + 16;
    #pragma unroll
    for (int j = 0; j < 8; j++) {
      pob[qrA * 128 + j * 16 + lane16] = f2bf(oA[j][r]);
      pob[qrB * 128 + j * 16 + lane16] = f2bf(oB[j][r]);
    }
    if (lane16 == 0) {
      pl[slot * 128 + qrA] = olA[r];
      pl[slot * 128 + qrB] = olB[r];
    }
  }
}

// ---------------- reduce: ALL qq groups, 128-row slots ----------------
__global__ __launch_bounds__(256) void reduce_kernel(const u16* __restrict__ po,
                                                     const float* __restrict__ pl,
                                                     u16* __restrict__ attn) {
  int bh = blockIdx.x >> 4, qq = blockIdx.x & 15;
  int tid = threadIdx.x;
  int nch = (4 * qq + 19) >> 4;
  int qrow = tid >> 1;          // 0..127
  int d0 = (tid & 1) * 64;      // 64 cols per thread
  float acc[64];
  #pragma unroll
  for (int i = 0; i < 64; i++) acc[i] = 0.0f;
  float l = 0.0f;
  int slot0 = (bh * 16 + qq) * 4;
  for (int c = 0; c < nch; c++) {
    int slot = slot0 + c;
    l += pl[slot * 128 + qrow];
    const short8* p = (const short8*)(po + (size_t)slot * 16384 + qrow * 128 + d0);
    #pragma unroll
    for (int v = 0; v < 8; v++) {
      short8 pk = p[v];
      #pragma unroll
      for (int e = 0; e < 8; e++) acc[v * 8 + e] += bf2f((u16)pk[e]);
    }
  }
  float inv = rcpa(l);
  int b = bh >> 2, h = bh & 3, t = qq * 128 + qrow;
  u16* orow = attn + ((size_t)(b * TSEQ + t)) * CMOD + h * HD + d0;
  #pragma unroll
  for (int v = 0; v < 8; v++) {
    short8 ov;
    #pragma unroll
    for (int e = 0; e < 8; e++) ov[e] = (short)f2bf(acc[v * 8 + e] * inv);
    *(short8*)(orow + v * 8) = ov;
  }
}

extern "C" void kernel_launch(void* const* d_in, const int* in_sizes, int n_in,
                              void* d_out, int out_size, void* d_ws, size_t ws_size,
                              hipStream_t stream) {
  const float* x     = (const float*)d_in[0];
  const float* ln1g  = (const float*)d_in[1];
  const float* ln1b  = (const float*)d_in[2];
  const float* wqkv  = (const float*)d_in[3];
  const float* wproj = (const float*)d_in[4];
  const float* ln2g  = (const float*)d_in[5];
  const float* ln2b  = (const float*)d_in[6];
  const float* wff1  = (const float*)d_in[7];
  const float* wff2  = (const float*)d_in[8];
  float* out = (float*)d_out;
  char* ws = (char*)d_ws;

  u16* wt_qkv  = (u16*)(ws);
  u16* wt_proj = (u16*)(ws + 1572864);
  u16* wt_ff1  = (u16*)(ws + 2097152);
  u16* wt_ff2  = (u16*)(ws + 4194304);
  u16* ln_buf  = (u16*)(ws + 6291456);
  u16* q_buf   = (u16*)(ws + 14680064);
  u16* k_buf   = (u16*)(ws + 23068672);
  u16* vt_buf  = (u16*)(ws + 31457280);
  u16* attn    = (u16*)(ws + 39845888);
  float* x2    = (float*)(ws + 48234496);
  u16* h1      = (u16*)(ws + 65011712);
  // attention partials overlap x2/h1 region (dead before proj/FF1 write)
  u16* po      = (u16*)(ws + 48234496);   // 1024 slots x 128x128 bf16 = 33.5 MB
  float* pl    = (float*)(ws + 81788928); // 1024 x 128 f32 = 512 KB

  dim3 blk(256);
  prep_kernel<<<dim3(5120), blk, 0, stream>>>(x, ln1g, ln1b, wqkv, wproj, wff1, wff2,
                                              ln_buf, wt_qkv, wt_proj, wt_ff1, wt_ff2);

  gemm_kernel<0, 128><<<dim3(CQKV / 128, BT / 128), blk, 0, stream>>>(
      ln_buf, wt_qkv, CMOD, nullptr, nullptr, q_buf, k_buf, vt_buf);

  attn_kernel<<<dim3(NBAT * NH, 40), blk, 0, stream>>>(q_buf, k_buf, vt_buf, po, pl);

  reduce_kernel<<<dim3(256), blk, 0, stream>>>(po, pl, attn);

  gemm_kernel<1, 64><<<dim3(CMOD / 64, BT / 128), blk, 0, stream>>>(
      attn, wt_proj, CMOD, x, x2, nullptr, nullptr, nullptr);

  ln_kernel<<<dim3(BT / 4), blk, 0, stream>>>(x2, ln2g, ln2b, ln_buf);

  gemm_kernel<2, 128><<<dim3(DFF / 128, BT / 128), blk, 0, stream>>>(
      ln_buf, wt_ff1, CMOD, nullptr, nullptr, h1, nullptr, nullptr);

  gemm_kernel<3, 64><<<dim3(CMOD / 64, BT / 128), blk, 0, stream>>>(
      h1, wt_ff2, DFF, x2, out, nullptr, nullptr, nullptr);
}